// Round 6
// baseline (119.728 us; speedup 1.0000x reference)
//
#include <hip/hip_runtime.h>

// rmsdLoss via associative affine scan — R16.
// R15 post-mortem: more waves/block changed nothing (occ 30%, VALU 45%) ->
// stall is a SHARED per-CU resource. Theory: L1/TA path. Per-lane chunk
// loads stride 32-64B -> ~1570 cache-line transactions/wave (~100KB L1
// traffic for 8.5KB useful) -> ~21us/CU of L1 occupancy, same order as the
// ~20us VALU issue time, and unhideable by occupancy. Explains R14 (misaligned
// dwordx4 = 2 lines/lane -> 62us) and why FETCH_SIZE stays 33MB (L2 absorbs;
// cost is CU<->L2 transactions, not HBM).
// R16 = R11 core (matrix scan, CHUNK=8, 1 row/block, grid 2048 — proven
// 43.6us) with ONE change: coalesced LDS staging. 256 threads stage both
// rows (2x4087 floats) tid-linearly (32 scalar loads/thread, 256B/instr
// fully coalesced -> 4 line-transactions per load instead of 64). Chunk
// values then read from LDS. XOR swizzle idx^(((idx>>5)&15)<<1) (involution):
// writes stay conflict-free (bijective per 32-run), strided reads capped at
// ~4-way (1.58x, m136). Ls arena (32KB) is dead after the register reads ->
// pos arena aliases Ls[0] (union; Tbuf barrier already separates). LDS 33KB
// -> 4 blocks/CU.
// Predicted: dur ~28-33us, VALUBusy 60-75%, conflicts ~50-300K, WRITE ~64B.
// If unchanged -> L1 theory dead, pivot to VALU instruction reduction.

#define LROW  4087
#define NSTEP 1021
#define NROW  2048
#define CHUNK 8
#define EPSF  1e-6f
#define INVMEAN (1.0f / (2048.0f * 1024.0f * 3.0f))
#define SWZ(i) ((i) ^ ((((i) >> 5) & 15) << 1))

__device__ __forceinline__ float frcp(float x){ return __builtin_amdgcn_rcpf(x); }
__device__ __forceinline__ float frsq(float x){ return __builtin_amdgcn_rsqf(x); }

struct Xf { float f[12]; };  // COLUMN-major: f[0..2]=c0, f[3..5]=c1, f[6..8]=c2, f[9..11]=t

__device__ __forceinline__ Xf xident(){
  Xf X;
  X.f[0]=1.f; X.f[1]=0.f; X.f[2]=0.f;
  X.f[3]=0.f; X.f[4]=1.f; X.f[5]=0.f;
  X.f[6]=0.f; X.f[7]=0.f; X.f[8]=1.f;
  X.f[9]=0.f; X.f[10]=0.f; X.f[11]=0.f;
  return X;
}

// A applied first, then B: C.M = A.M*B.M (columns), C.t = A.t + A.M*B.t
__device__ __forceinline__ Xf xcombine(const Xf& A, const Xf& B){
  Xf C;
  #pragma unroll
  for (int c3 = 0; c3 < 12; c3 += 3){
    const float bx = B.f[c3], by = B.f[c3+1], bz = B.f[c3+2];
    C.f[c3]   = A.f[0]*bx + A.f[3]*by + A.f[6]*bz;
    C.f[c3+1] = A.f[1]*bx + A.f[4]*by + A.f[7]*bz;
    C.f[c3+2] = A.f[2]*bx + A.f[5]*by + A.f[8]*bz;
  }
  C.f[9] += A.f[9]; C.f[10] += A.f[10]; C.f[11] += A.f[11];
  return C;
}

__device__ __forceinline__ void xstepP(Xf& X, float Px, float Py, float Pz){
  const float l2 = Px*Px + Py*Py + Pz*Pz;
  const float q  = frsq(l2);
  const float hx = q*Px, hy = q*Py, hz = q*Pz;
  const float ist = frsq(fmaxf(hy*hy + hz*hz, 1e-12f));   // 1/st, cancellation-free
  const float ux = X.f[0]*Px + X.f[3]*Py + X.f[6]*Pz;
  const float uy = X.f[1]*Px + X.f[4]*Py + X.f[7]*Pz;
  const float uz = X.f[2]*Px + X.f[5]*Py + X.f[8]*Pz;
  X.f[9] += ux; X.f[10] += uy; X.f[11] += uz;
  const float n0x = q*ux, n0y = q*uy, n0z = q*uz;
  const float n1x = ist*(hx*n0x - X.f[0]);
  const float n1y = ist*(hx*n0y - X.f[1]);
  const float n1z = ist*(hx*n0z - X.f[2]);
  const float n2x = ist*(hy*X.f[6] - hz*X.f[3]);
  const float n2y = ist*(hy*X.f[7] - hz*X.f[4]);
  const float n2z = ist*(hy*X.f[8] - hz*X.f[5]);
  X.f[0]=n0x; X.f[1]=n0y; X.f[2]=n0z;
  X.f[3]=n1x; X.f[4]=n1y; X.f[5]=n1z;
  X.f[6]=n2x; X.f[7]=n2y; X.f[8]=n2z;
}

__device__ __forceinline__ void xinitP(Xf& X, float Px, float Py, float Pz){
  const float l2 = Px*Px + Py*Py + Pz*Pz;
  const float q  = frsq(l2);
  const float hx = q*Px, hy = q*Py, hz = q*Pz;
  const float s2 = fmaxf(hy*hy + hz*hz, 1e-12f);
  const float ist = frsq(s2);
  const float st  = s2 * ist;
  X.f[0]=hx;        X.f[1]=hy;          X.f[2]=hz;
  X.f[3]=-st;       X.f[4]=hx*hy*ist;   X.f[5]=hx*hz*ist;
  X.f[6]=0.f;       X.f[7]=-hz*ist;     X.f[8]=hy*ist;
  X.f[9]=Px;        X.f[10]=Py;        X.f[11]=Pz;
}

__global__ void __launch_bounds__(256, 4)
rmsd_kernel(const float* __restrict__ pred, const float* __restrict__ targ,
            float* __restrict__ out){
  __shared__ float Ls[2][4096];       // 32 KB staging; Ls[0] reused as pos arena
  __shared__ float Tbuf[2][12];       // per-chain half-0 inclusive totals
  __shared__ float ini[3];            // pred a1x, a2x, a2y
  __shared__ float part;              // targ half-1 reduced partial

  const int row  = blockIdx.x;
  const int tid  = threadIdx.x;
  const int ln   = tid & 63;
  const int wv   = tid >> 6;          // 0..3
  const int c    = wv >> 1;           // 0 = pred, 1 = targ
  const int half = wv & 1;            // which half of the chain
  const int lid  = (half << 6) | ln;  // 0..127 lane-in-chain
  const int j0   = lid * CHUNK;       // first step owned (<= 1016)

  const float* __restrict__ vp = pred + (size_t)row * LROW;
  const float* __restrict__ vt = targ + (size_t)row * LROW;
  const float* __restrict__ v = c ? vt : vp;
  const float cl = c ? 1e30f : 1.0f;  // reference clips pred only

  // ---- coalesced staging: tid-linear, 256B/instr; swizzled LDS dest ----
  #pragma unroll
  for (int i = 0; i < 15; ++i){
    const int idx = tid + (i << 8);            // < 3840+256 always in-bounds
    Ls[0][SWZ(idx)] = vp[idx];
  }
  { const int idx = tid + (15 << 8); if (idx < LROW) Ls[0][SWZ(idx)] = vp[idx]; }
  #pragma unroll
  for (int i = 0; i < 15; ++i){
    const int idx = tid + (i << 8);
    Ls[1][SWZ(idx)] = vt[idx];
  }
  { const int idx = tid + (15 << 8); if (idx < LROW) Ls[1][SWZ(idx)] = vt[idx]; }

  // broadcast fold inputs (wave-uniform -> scalar loads, K$ path)
  const float rb0 = fminf(fmaxf(v[3064], -cl), cl);
  const float rd0 = fminf(fmaxf(v[2042], -cl), cl);
  const float rb1w= fminf(fmaxf(v[3065], -cl), cl);

  __syncthreads();

  // ---- per-lane chunk values from LDS (~4-way conflicts max) ----
  const float* __restrict__ Lc = Ls[c];
  float s0[CHUNK], s1[CHUNK], dd[CHUNK], bv[CHUNK+1];
  #pragma unroll
  for (int k = 0; k < CHUNK; ++k){
    s0[k] = Lc[SWZ(2*(j0+k))];
    s1[k] = Lc[SWZ(2*(j0+k)+1)];
    dd[k] = Lc[SWZ(2043 + j0 + k)];
  }
  #pragma unroll
  for (int m = 0; m <= CHUNK; ++m){
    int ix = 3065 + j0 + m;
    if (ix > 4086) ix = 4086;        // tail lane clamp (garbage steps guarded)
    bv[m] = Lc[SWZ(ix)];
  }
  #pragma unroll
  for (int m = 0; m <= CHUNK; ++m)
    bv[m] = fmaf(fminf(fmaxf(bv[m], -cl), cl), 1.05f, 1.95f);

  // ---- per-step P in lane-local frame ----
  float Px[CHUNK], Py[CHUNK], Pz[CHUNK];
  #pragma unroll
  for (int k = 0; k < CHUNK; ++k){
    const float a0 = fminf(fmaxf(s0[k], -cl), cl);
    const float a1 = fminf(fmaxf(s1[k], -cl), cl);
    const float d  = fmaf(fminf(fmaxf(dd[k], -cl), cl), 1.75f, 3.25f);
    const float b1 = bv[k], b2 = bv[k+1];
    float ct = (b1*b1 + b2*b2 - d*d) * frcp(2.0f*b1*b2);
    ct = fminf(fmaxf(ct, -1.0f + EPSF), 1.0f - EPSF);
    const float st = sqrtf(fmaxf(1.0f - ct*ct, 0.0f));
    const float r2 = a0*a0 + a1*a1;
    const bool ok = r2 > 1e-36f;
    const float ir = ok ? frcp(sqrtf(r2)) : 0.0f;
    const float scv = a0 * ir;
    const float ccv = ok ? a1 * ir : 1.0f;
    Px[k] = -b2 * ct;
    Py[k] = b2 * st * ccv;
    Pz[k] = b2 * st * scv;
  }

  // ---- per-lane chunk compose (8 steps), snapshot local-prefix translations ----
  Xf X;
  float tl[CHUNK][3];
  xinitP(X, Px[0], Py[0], Pz[0]);
  tl[0][0]=X.f[9]; tl[0][1]=X.f[10]; tl[0][2]=X.f[11];
  #pragma unroll
  for (int k = 1; k < CHUNK; ++k){
    if (j0 + k < NSTEP) xstepP(X, Px[k], Py[k], Pz[k]);
    tl[k][0]=X.f[9]; tl[k][1]=X.f[10]; tl[k][2]=X.f[11];
  }

  // ---- in-wave inclusive scan (Hillis-Steele, non-commutative) ----
  #pragma unroll
  for (int off = 1; off < 64; off <<= 1){
    Xf o;
    #pragma unroll
    for (int i = 0; i < 12; ++i) o.f[i] = __shfl_up(X.f[i], off);
    if (ln >= off) X = xcombine(o, X);
  }

  // half-0 publishes its chain-half total for the cross-wave prefix
  if (half == 0 && ln == 63){
    #pragma unroll
    for (int i = 0; i < 12; ++i) Tbuf[c][i] = X.f[i];
  }

  Xf E;
  #pragma unroll
  for (int i = 0; i < 12; ++i) E.f[i] = __shfl_up(X.f[i], 1);
  if (ln == 0) E = xident();

  __syncthreads();   // Tbuf visible; all staged reads long done (Ls[0] now dead)

  if (half == 1){    // prepend half-0 total (ln==0: E=ident -> E=T)
    Xf T;
    #pragma unroll
    for (int i = 0; i < 12; ++i) T.f[i] = Tbuf[c][i];
    E = xcombine(T, E);
  }

  // ---- fold (F0, a2): G = F0*E.M ; G.t = a2 + F0*E.t ----
  const float bl0 = fmaf(rb0,  1.05f, 1.95f);
  const float d0  = fmaf(rd0,  1.75f, 3.25f);
  const float b1f = fmaf(rb1w, 1.05f, 1.95f);
  float ct0 = (bl0*bl0 + b1f*b1f - d0*d0) * frcp(2.0f*bl0*b1f);
  ct0 = fminf(fmaxf(ct0, -1.0f + EPSF), 1.0f - EPSF);
  const float st0 = sqrtf(fmaxf(1.0f - ct0*ct0, 0.0f));
  const float a1x = bl0;
  const float a2x = bl0 - b1f*ct0;
  const float a2y = b1f*st0;

  Xf G;   // F0 rows: (-ct0,-st0,0),(st0,-ct0,0),(0,0,1) applied to each column + t
  #pragma unroll
  for (int c3 = 0; c3 < 12; c3 += 3){
    const float ex = E.f[c3], ey = E.f[c3+1], ez = E.f[c3+2];
    G.f[c3]   = -ct0*ex - st0*ey;
    G.f[c3+1] =  st0*ex - ct0*ey;
    G.f[c3+2] =  ez;
  }
  G.f[9] += a2x; G.f[10] += a2y;

  // ---- positions p_k = G.t + G.M * tl[k]  (in place) ----
  #pragma unroll
  for (int k = 0; k < CHUNK; ++k){
    const float tx = tl[k][0], ty = tl[k][1], tz = tl[k][2];
    tl[k][0] = G.f[9]  + G.f[0]*tx + G.f[3]*ty + G.f[6]*tz;
    tl[k][1] = G.f[10] + G.f[1]*tx + G.f[4]*ty + G.f[7]*tz;
    tl[k][2] = G.f[11] + G.f[2]*tx + G.f[5]*ty + G.f[8]*tz;
  }

  // ---- pred publishes positions into dead Ls[0] (pitch 25, max 3198 < 4096) ----
  float* __restrict__ pos = &Ls[0][0];
  if (c == 0){
    #pragma unroll
    for (int k = 0; k < CHUNK; ++k){
      if (j0 + k < NSTEP){
        const int o = lid*25 + 3*k;
        pos[o] = tl[k][0]; pos[o+1] = tl[k][1]; pos[o+2] = tl[k][2];
      }
    }
    if (lid == 0){ ini[0] = a1x; ini[1] = a2x; ini[2] = a2y; }
  }
  __syncthreads();

  // ---- targ waves: diff + reduce ----
  float acc = 0.0f;
  if (c == 1){
    if (lid == 0){
      const float dx = ini[0] - a1x;   // a1 differs only in x; a0 diff = 0
      const float dy = ini[1] - a2x;   // a2 differs in x,y (z = 0)
      const float dz = ini[2] - a2y;
      acc = dx*dx + dy*dy + dz*dz;
    }
    #pragma unroll
    for (int k = 0; k < CHUNK; ++k){
      if (j0 + k < NSTEP){
        const int o = lid*25 + 3*k;
        const float dx = pos[o]   - tl[k][0];
        const float dy = pos[o+1] - tl[k][1];
        const float dz = pos[o+2] - tl[k][2];
        acc = fmaf(dx, dx, acc);
        acc = fmaf(dy, dy, acc);
        acc = fmaf(dz, dz, acc);
      }
    }
    #pragma unroll
    for (int off = 32; off > 0; off >>= 1) acc += __shfl_down(acc, off);
    if (half == 1 && ln == 0) part = acc;   // targ half-1 partial
  }
  __syncthreads();
  if (wv == 2 && ln == 0) atomicAdd(out, (acc + part) * INVMEAN);  // 1 atomic/block
}

extern "C" void kernel_launch(void* const* d_in, const int* in_sizes, int n_in,
                              void* d_out, int out_size, void* d_ws, size_t ws_size,
                              hipStream_t stream) {
  const float* pred = (const float*)d_in[0];
  const float* targ = (const float*)d_in[1];
  float* out = (float*)d_out;

  hipMemsetAsync(d_out, 0, sizeof(float), stream);
  rmsd_kernel<<<NROW, 256, 0, stream>>>(pred, targ, out);
}

// Round 7
// 108.244 us; speedup vs baseline: 1.1061x; 1.1061x over previous
//
#include <hip/hip_runtime.h>

// rmsdLoss via associative affine scan — R17.
// R10-R16 post-mortem: SIX structural variants (CHUNK 8/16, 4/8 waves/blk,
// vectorized loads, quat scan, LDS staging) ALL land at 43.5-47us. The one
// thing none of them changed: every block ends with atomicAdd(out, ...) to a
// SINGLE address — 2048 serialized same-address L2 RMWs at ~20-50cy each.
// 2048 x 50cy = 42.7us @2.4GHz = exactly the observed floor. Drain-tail also
// explains the stuck time-averaged counters (occ ~30%, VALU ~45-50%: near-idle
// tail drags the averages) and why R12/R13 were slower only when their compute
// exceeded the atomic floor.
// R17 = R11 core byte-for-byte (proven best) with ONE change: no atomic.
// Each block stores its partial to d_ws[row] (plain store, no contention);
// a second 1-block kernel reduces 2048 partials -> out (coalesced, ~3us).
// hipMemsetAsync dropped (reduce kernel overwrites out).
// Predicted: rmsd_kernel 43.6 -> ~20-30us, VALUBusy -> 65-90%, occupancy up;
// bench ~100-107us. If rmsd stays ~43us -> theory dead, pivot to 6-float scan.

#define LROW  4087
#define NSTEP 1021
#define NROW  2048
#define CHUNK 8
#define EPSF  1e-6f
#define INVMEAN (1.0f / (2048.0f * 1024.0f * 3.0f))

__device__ __forceinline__ float frcp(float x){ return __builtin_amdgcn_rcpf(x); }
__device__ __forceinline__ float frsq(float x){ return __builtin_amdgcn_rsqf(x); }

struct Xf { float f[12]; };  // COLUMN-major: f[0..2]=c0, f[3..5]=c1, f[6..8]=c2, f[9..11]=t

__device__ __forceinline__ Xf xident(){
  Xf X;
  X.f[0]=1.f; X.f[1]=0.f; X.f[2]=0.f;
  X.f[3]=0.f; X.f[4]=1.f; X.f[5]=0.f;
  X.f[6]=0.f; X.f[7]=0.f; X.f[8]=1.f;
  X.f[9]=0.f; X.f[10]=0.f; X.f[11]=0.f;
  return X;
}

// A applied first, then B: C.M = A.M*B.M (columns), C.t = A.t + A.M*B.t
__device__ __forceinline__ Xf xcombine(const Xf& A, const Xf& B){
  Xf C;
  #pragma unroll
  for (int c3 = 0; c3 < 12; c3 += 3){
    const float bx = B.f[c3], by = B.f[c3+1], bz = B.f[c3+2];
    C.f[c3]   = A.f[0]*bx + A.f[3]*by + A.f[6]*bz;
    C.f[c3+1] = A.f[1]*bx + A.f[4]*by + A.f[7]*bz;
    C.f[c3+2] = A.f[2]*bx + A.f[5]*by + A.f[8]*bz;
  }
  C.f[9] += A.f[9]; C.f[10] += A.f[10]; C.f[11] += A.f[11];
  return C;
}

__device__ __forceinline__ void xstepP(Xf& X, float Px, float Py, float Pz){
  const float l2 = Px*Px + Py*Py + Pz*Pz;
  const float q  = frsq(l2);
  const float hx = q*Px, hy = q*Py, hz = q*Pz;
  const float ist = frsq(fmaxf(hy*hy + hz*hz, 1e-12f));   // 1/st, cancellation-free
  const float ux = X.f[0]*Px + X.f[3]*Py + X.f[6]*Pz;
  const float uy = X.f[1]*Px + X.f[4]*Py + X.f[7]*Pz;
  const float uz = X.f[2]*Px + X.f[5]*Py + X.f[8]*Pz;
  X.f[9] += ux; X.f[10] += uy; X.f[11] += uz;
  const float n0x = q*ux, n0y = q*uy, n0z = q*uz;
  const float n1x = ist*(hx*n0x - X.f[0]);
  const float n1y = ist*(hx*n0y - X.f[1]);
  const float n1z = ist*(hx*n0z - X.f[2]);
  const float n2x = ist*(hy*X.f[6] - hz*X.f[3]);
  const float n2y = ist*(hy*X.f[7] - hz*X.f[4]);
  const float n2z = ist*(hy*X.f[8] - hz*X.f[5]);
  X.f[0]=n0x; X.f[1]=n0y; X.f[2]=n0z;
  X.f[3]=n1x; X.f[4]=n1y; X.f[5]=n1z;
  X.f[6]=n2x; X.f[7]=n2y; X.f[8]=n2z;
}

__device__ __forceinline__ void xinitP(Xf& X, float Px, float Py, float Pz){
  const float l2 = Px*Px + Py*Py + Pz*Pz;
  const float q  = frsq(l2);
  const float hx = q*Px, hy = q*Py, hz = q*Pz;
  const float s2 = fmaxf(hy*hy + hz*hz, 1e-12f);
  const float ist = frsq(s2);
  const float st  = s2 * ist;
  X.f[0]=hx;        X.f[1]=hy;          X.f[2]=hz;
  X.f[3]=-st;       X.f[4]=hx*hy*ist;   X.f[5]=hx*hz*ist;
  X.f[6]=0.f;       X.f[7]=-hz*ist;     X.f[8]=hy*ist;
  X.f[9]=Px;        X.f[10]=Py;        X.f[11]=Pz;
}

__global__ void __launch_bounds__(256, 4)
rmsd_kernel(const float* __restrict__ pred, const float* __restrict__ targ,
            float* __restrict__ ws){
  __shared__ float pos[128*25 + 8];   // pitch 25 (coprime w/ 32 banks): 12.8 KB
  __shared__ float Tbuf[2][12];       // per-chain half-0 inclusive totals
  __shared__ float ini[3];            // pred a1x, a2x, a2y
  __shared__ float part;              // targ half-1 reduced partial

  const int row  = blockIdx.x;
  const int tid  = threadIdx.x;
  const int ln   = tid & 63;
  const int wv   = tid >> 6;          // 0..3
  const int c    = wv >> 1;           // 0 = pred, 1 = targ
  const int half = wv & 1;            // which half of the chain
  const int lid  = (half << 6) | ln;  // 0..127 lane-in-chain
  const int j0   = lid * CHUNK;       // first step owned (<= 1016)

  const float* __restrict__ v = (c ? targ : pred) + (size_t)row * LROW;
  const float cl = c ? 1e30f : 1.0f;  // reference clips pred only

  // broadcast fold inputs (wave-uniform -> scalar loads)
  const float rb0 = fminf(fmaxf(v[3064], -cl), cl);
  const float rd0 = fminf(fmaxf(v[2042], -cl), cl);
  const float rb1w= fminf(fmaxf(v[3065], -cl), cl);

  // ---- batch per-lane loads: 33 contiguous dwords, all independent ----
  float s0[CHUNK], s1[CHUNK], dd[CHUNK], bv[CHUNK+1];
  #pragma unroll
  for (int k = 0; k < CHUNK; ++k){
    s0[k] = v[2*(j0+k)];
    s1[k] = v[2*(j0+k)+1];
    dd[k] = v[2043 + j0 + k];
  }
  #pragma unroll
  for (int m = 0; m <= CHUNK; ++m){
    int ix = 3065 + j0 + m;
    if (ix > 4086) ix = 4086;        // tail lane clamp (garbage steps guarded)
    bv[m] = v[ix];
  }
  #pragma unroll
  for (int m = 0; m <= CHUNK; ++m)
    bv[m] = fmaf(fminf(fmaxf(bv[m], -cl), cl), 1.05f, 1.95f);

  // ---- per-step P in lane-local frame ----
  float Px[CHUNK], Py[CHUNK], Pz[CHUNK];
  #pragma unroll
  for (int k = 0; k < CHUNK; ++k){
    const float a0 = fminf(fmaxf(s0[k], -cl), cl);
    const float a1 = fminf(fmaxf(s1[k], -cl), cl);
    const float d  = fmaf(fminf(fmaxf(dd[k], -cl), cl), 1.75f, 3.25f);
    const float b1 = bv[k], b2 = bv[k+1];
    float ct = (b1*b1 + b2*b2 - d*d) * frcp(2.0f*b1*b2);
    ct = fminf(fmaxf(ct, -1.0f + EPSF), 1.0f - EPSF);
    const float st = sqrtf(fmaxf(1.0f - ct*ct, 0.0f));
    const float r2 = a0*a0 + a1*a1;
    const bool ok = r2 > 1e-36f;
    const float ir = ok ? frcp(sqrtf(r2)) : 0.0f;
    const float scv = a0 * ir;
    const float ccv = ok ? a1 * ir : 1.0f;
    Px[k] = -b2 * ct;
    Py[k] = b2 * st * ccv;
    Pz[k] = b2 * st * scv;
  }

  // ---- per-lane chunk compose (8 steps), snapshot local-prefix translations ----
  Xf X;
  float tl[CHUNK][3];
  xinitP(X, Px[0], Py[0], Pz[0]);
  tl[0][0]=X.f[9]; tl[0][1]=X.f[10]; tl[0][2]=X.f[11];
  #pragma unroll
  for (int k = 1; k < CHUNK; ++k){
    if (j0 + k < NSTEP) xstepP(X, Px[k], Py[k], Pz[k]);
    tl[k][0]=X.f[9]; tl[k][1]=X.f[10]; tl[k][2]=X.f[11];
  }

  // ---- in-wave inclusive scan (Hillis-Steele, non-commutative) ----
  #pragma unroll
  for (int off = 1; off < 64; off <<= 1){
    Xf o;
    #pragma unroll
    for (int i = 0; i < 12; ++i) o.f[i] = __shfl_up(X.f[i], off);
    if (ln >= off) X = xcombine(o, X);
  }

  // half-0 publishes its chain-half total for the cross-wave prefix
  if (half == 0 && ln == 63){
    #pragma unroll
    for (int i = 0; i < 12; ++i) Tbuf[c][i] = X.f[i];
  }

  Xf E;
  #pragma unroll
  for (int i = 0; i < 12; ++i) E.f[i] = __shfl_up(X.f[i], 1);
  if (ln == 0) E = xident();

  __syncthreads();   // Tbuf visible

  if (half == 1){    // prepend half-0 total (ln==0: E=ident -> E=T)
    Xf T;
    #pragma unroll
    for (int i = 0; i < 12; ++i) T.f[i] = Tbuf[c][i];
    E = xcombine(T, E);
  }

  // ---- fold (F0, a2): G = F0*E.M ; G.t = a2 + F0*E.t ----
  const float bl0 = fmaf(rb0,  1.05f, 1.95f);
  const float d0  = fmaf(rd0,  1.75f, 3.25f);
  const float b1f = fmaf(rb1w, 1.05f, 1.95f);
  float ct0 = (bl0*bl0 + b1f*b1f - d0*d0) * frcp(2.0f*bl0*b1f);
  ct0 = fminf(fmaxf(ct0, -1.0f + EPSF), 1.0f - EPSF);
  const float st0 = sqrtf(fmaxf(1.0f - ct0*ct0, 0.0f));
  const float a1x = bl0;
  const float a2x = bl0 - b1f*ct0;
  const float a2y = b1f*st0;

  Xf G;   // F0 rows: (-ct0,-st0,0),(st0,-ct0,0),(0,0,1) applied to each column + t
  #pragma unroll
  for (int c3 = 0; c3 < 12; c3 += 3){
    const float ex = E.f[c3], ey = E.f[c3+1], ez = E.f[c3+2];
    G.f[c3]   = -ct0*ex - st0*ey;
    G.f[c3+1] =  st0*ex - ct0*ey;
    G.f[c3+2] =  ez;
  }
  G.f[9] += a2x; G.f[10] += a2y;

  // ---- positions p_k = G.t + G.M * tl[k]  (in place) ----
  #pragma unroll
  for (int k = 0; k < CHUNK; ++k){
    const float tx = tl[k][0], ty = tl[k][1], tz = tl[k][2];
    tl[k][0] = G.f[9]  + G.f[0]*tx + G.f[3]*ty + G.f[6]*tz;
    tl[k][1] = G.f[10] + G.f[1]*tx + G.f[4]*ty + G.f[7]*tz;
    tl[k][2] = G.f[11] + G.f[2]*tx + G.f[5]*ty + G.f[8]*tz;
  }

  // ---- pred publishes positions (pitch 25 -> conflict-free) ----
  if (c == 0){
    #pragma unroll
    for (int k = 0; k < CHUNK; ++k){
      if (j0 + k < NSTEP){
        const int o = lid*25 + 3*k;
        pos[o] = tl[k][0]; pos[o+1] = tl[k][1]; pos[o+2] = tl[k][2];
      }
    }
    if (lid == 0){ ini[0] = a1x; ini[1] = a2x; ini[2] = a2y; }
  }
  __syncthreads();

  // ---- targ waves: diff + reduce ----
  float acc = 0.0f;
  if (c == 1){
    if (lid == 0){
      const float dx = ini[0] - a1x;   // a1 differs only in x; a0 diff = 0
      const float dy = ini[1] - a2x;   // a2 differs in x,y (z = 0)
      const float dz = ini[2] - a2y;
      acc = dx*dx + dy*dy + dz*dz;
    }
    #pragma unroll
    for (int k = 0; k < CHUNK; ++k){
      if (j0 + k < NSTEP){
        const int o = lid*25 + 3*k;
        const float dx = pos[o]   - tl[k][0];
        const float dy = pos[o+1] - tl[k][1];
        const float dz = pos[o+2] - tl[k][2];
        acc = fmaf(dx, dx, acc);
        acc = fmaf(dy, dy, acc);
        acc = fmaf(dz, dz, acc);
      }
    }
    #pragma unroll
    for (int off = 32; off > 0; off >>= 1) acc += __shfl_down(acc, off);
    if (half == 1 && ln == 0) part = acc;   // targ half-1 partial
  }
  __syncthreads();
  // plain store, ZERO contention (was: 2048 same-address atomics = the floor)
  if (wv == 2 && ln == 0) ws[row] = acc + part;
}

// 1 block: reduce 2048 per-row partials -> out. 8 coalesced loads/thread.
__global__ void __launch_bounds__(256, 1)
reduce_kernel(const float* __restrict__ ws, float* __restrict__ out){
  __shared__ float wsum[4];
  const int tid = threadIdx.x;
  float a = 0.0f;
  #pragma unroll
  for (int i = 0; i < 8; ++i) a += ws[tid + (i << 8)];
  #pragma unroll
  for (int off = 32; off > 0; off >>= 1) a += __shfl_down(a, off);
  if ((tid & 63) == 0) wsum[tid >> 6] = a;
  __syncthreads();
  if (tid == 0) out[0] = (wsum[0] + wsum[1] + wsum[2] + wsum[3]) * INVMEAN;
}

extern "C" void kernel_launch(void* const* d_in, const int* in_sizes, int n_in,
                              void* d_out, int out_size, void* d_ws, size_t ws_size,
                              hipStream_t stream) {
  const float* pred = (const float*)d_in[0];
  const float* targ = (const float*)d_in[1];
  float* out = (float*)d_out;
  float* ws  = (float*)d_ws;   // needs 2048 floats = 8 KB

  rmsd_kernel<<<NROW, 256, 0, stream>>>(pred, targ, ws);
  reduce_kernel<<<1, 256, 0, stream>>>(ws, out);
}